// Round 19
// baseline (1317.105 us; speedup 1.0000x reference)
//
#include <hip/hip_runtime.h>
#include <hip/hip_bf16.h>
#include <stdint.h>
#include <math.h>

#define DD 4096

typedef float v4f __attribute__((ext_vector_type(4)));
typedef short v8s __attribute__((ext_vector_type(8)));

__device__ __forceinline__ unsigned short f2bf(float f){
  union { float f; uint32_t u; } v; v.f = f;
  uint32_t u = v.u;
  uint32_t r = (u + 0x7fffu + ((u >> 16) & 1u)) >> 16;
  return (unsigned short)r;
}
__device__ __forceinline__ ushort4 cvt4(float4 v){
  ushort4 o; o.x = f2bf(v.x); o.y = f2bf(v.y); o.z = f2bf(v.z); o.w = f2bf(v.w); return o;
}
__device__ __forceinline__ float dot4(float4 a, float4 b){
  return a.x*b.x + a.y*b.y + a.z*b.z + a.w*b.w;
}
__device__ __forceinline__ float wred(float v){
  #pragma unroll
  for (int m = 32; m >= 1; m >>= 1) v += __shfl_xor(v, m, 64);
  return v;
}
__device__ __forceinline__ float fast_tanh(float x){
  float e = __expf(2.f * x);
  return __fdividef(e - 1.f, e + 1.f);
}
__device__ __forceinline__ void gload16(const void* g, void* l){
  __builtin_amdgcn_global_load_lds((const __attribute__((address_space(1))) void*)g,
                                   (__attribute__((address_space(3))) void*)l, 16, 0, 0);
}

// ---------------- fp32 -> bf16 convert: grid-strided, 8 float4/thread ----------------
__global__ __launch_bounds__(256) void k_convert_bf16(const float* __restrict__ src,
                                                      unsigned short* __restrict__ dst, int n4){
  int i = blockIdx.x * 256 + threadIdx.x;
  #pragma unroll
  for (int q = 0; q < 8; ++q){
    if (i < n4){
      float4 v = ((const float4*)src)[i];
      ((ushort4*)dst)[i] = cvt4(v);
    }
    i += 524288;   // 2048 blocks * 256 threads
  }
}

// ---------------- cL[k]=dot(ln_w,Wd[k]); cB[k]=dot(ln_b,Wd[k]) ----------------
__global__ __launch_bounds__(256) void k_cwd(const float* __restrict__ lnw,
    const float* __restrict__ lnb, const float* __restrict__ wd,
    float* __restrict__ cL, float* __restrict__ cB)
{
  const int tid = threadIdx.x;
  float aL[8], aB[8];
  #pragma unroll
  for (int k = 0; k < 8; ++k){ aL[k] = 0.f; aB[k] = 0.f; }
  for (int i = tid; i < 1024; i += 256){
    float4 w4 = ((const float4*)lnw)[i];
    float4 b4 = ((const float4*)lnb)[i];
    #pragma unroll
    for (int k = 0; k < 8; ++k){
      float4 d4 = ((const float4*)wd)[(size_t)k*1024 + i];
      aL[k] += dot4(w4, d4);
      aB[k] += dot4(b4, d4);
    }
  }
  __shared__ float sp[4][16];
  const int w = tid >> 6, lane = tid & 63;
  #pragma unroll
  for (int k = 0; k < 8; ++k){
    float v = wred(aL[k]); if (lane == 0) sp[w][k] = v;
    v = wred(aB[k]);       if (lane == 0) sp[w][8+k] = v;
  }
  __syncthreads();
  if (tid < 8)       cL[tid]   = sp[0][tid] + sp[1][tid] + sp[2][tid] + sp[3][tid];
  else if (tid < 16) cB[tid-8] = sp[0][tid] + sp[1][tid] + sp[2][tid] + sp[3][tid];
}

// ---------------- row pass A: t = x.A^T (+ x->bf16), 4 rows/block [r18-measured] ----------------
__global__ __launch_bounds__(256) void k_rows_t(const float* __restrict__ x,
    const float* __restrict__ Am, float* __restrict__ t_ws,
    unsigned short* __restrict__ xbf, int writeBf)
{
  const int row0 = blockIdx.x * 4;
  const int tid = threadIdx.x;
  float dA[4][16];
  #pragma unroll
  for (int rr = 0; rr < 4; ++rr)
    #pragma unroll
    for (int r = 0; r < 16; ++r) dA[rr][r] = 0.f;

  #pragma unroll
  for (int i = 0; i < 4; ++i){
    const int d4 = tid + 256*i;
    float4 xv[4];
    #pragma unroll
    for (int rr = 0; rr < 4; ++rr){
      xv[rr] = ((const float4*)x)[(size_t)(row0+rr)*1024 + d4];
      if (writeBf) ((ushort4*)xbf)[(size_t)(row0+rr)*1024 + d4] = cvt4(xv[rr]);
    }
    #pragma unroll
    for (int r = 0; r < 16; ++r){
      float4 a4 = ((const float4*)Am)[(size_t)r*1024 + d4];
      #pragma unroll
      for (int rr = 0; rr < 4; ++rr) dA[rr][r] += dot4(xv[rr], a4);
    }
  }
  __shared__ float sp[4][64];
  const int w = tid >> 6, lane = tid & 63;
  #pragma unroll
  for (int rr = 0; rr < 4; ++rr)
    #pragma unroll
    for (int r = 0; r < 16; ++r){
      float v = wred(dA[rr][r]);
      if (lane == 0) sp[w][rr*16 + r] = v;
    }
  __syncthreads();
  if (tid < 64){
    t_ws[(size_t)row0*16 + tid] = sp[0][tid] + sp[1][tid] + sp[2][tid] + sp[3][tid];
  }
}

// ---------------- row pass B: bk = silu(LN(x).Wd^T), 4 rows/block [r18-measured] ----------------
__global__ __launch_bounds__(256) void k_rows_b(const float* __restrict__ x,
    const float* __restrict__ lnw, const float* __restrict__ wd,
    const float* __restrict__ cL, const float* __restrict__ cB,
    float* __restrict__ bk_ws)
{
  const int row0 = blockIdx.x * 4;
  const int tid = threadIdx.x;
  float sum[4] = {0,0,0,0}, ssq[4] = {0,0,0,0};
  float dW[4][8];
  #pragma unroll
  for (int rr = 0; rr < 4; ++rr)
    #pragma unroll
    for (int k = 0; k < 8; ++k) dW[rr][k] = 0.f;

  #pragma unroll
  for (int i = 0; i < 4; ++i){
    const int d4 = tid + 256*i;
    float4 w4 = ((const float4*)lnw)[d4];
    float4 xv[4];
    #pragma unroll
    for (int rr = 0; rr < 4; ++rr){
      xv[rr] = ((const float4*)x)[(size_t)(row0+rr)*1024 + d4];
      sum[rr] += xv[rr].x + xv[rr].y + xv[rr].z + xv[rr].w;
      ssq[rr] += dot4(xv[rr], xv[rr]);
    }
    #pragma unroll
    for (int k = 0; k < 8; ++k){
      float4 wk = ((const float4*)wd)[(size_t)k*1024 + d4];
      float4 lw; lw.x = w4.x*wk.x; lw.y = w4.y*wk.y; lw.z = w4.z*wk.z; lw.w = w4.w*wk.w;
      #pragma unroll
      for (int rr = 0; rr < 4; ++rr) dW[rr][k] += dot4(xv[rr], lw);
    }
  }
  __shared__ float sp[4][40];
  const int w = tid >> 6, lane = tid & 63;
  #pragma unroll
  for (int rr = 0; rr < 4; ++rr){
    float v;
    v = wred(sum[rr]); if (lane == 0) sp[w][rr*10 + 0] = v;
    v = wred(ssq[rr]); if (lane == 0) sp[w][rr*10 + 1] = v;
    #pragma unroll
    for (int k = 0; k < 8; ++k){
      v = wred(dW[rr][k]); if (lane == 0) sp[w][rr*10 + 2 + k] = v;
    }
  }
  __syncthreads();
  __shared__ float st[40];
  if (tid < 40) st[tid] = sp[0][tid] + sp[1][tid] + sp[2][tid] + sp[3][tid];
  __syncthreads();
  if (tid < 32){
    const int rr = tid >> 3, k = tid & 7;
    const float s  = st[rr*10 + 0];
    const float s2 = st[rr*10 + 1];
    const float mu = s * (1.f/4096.f);
    const float var = s2 * (1.f/4096.f) - mu*mu;
    const float istd = rsqrtf(var + 1e-5f);
    const float raw = istd*st[rr*10 + 2 + k] - mu*istd*cL[k] + cB[k];
    bk_ws[(size_t)(row0+rr)*8 + k] = raw / (1.f + __expf(-raw));   // silu
  }
}

// ---------------- fused GEMM: r16 structure + XCD-square map + fast_tanh epilogue ----
// K-loop unchanged from the measured-356µs r16 build (phase-split, 3-buf, W4
// counted ledger, kperm/sx swizzle conflicts==0, setprio).
// Change 1: XCD map 4x16 -> 8x8 panels/XCD (per-XCD unique bytes 40->32 MB;
//           predicted FETCH 345 -> ~265 MB).
// Change 2: epilogue tanhf -> fast_tanh. r4's VGPR objection doesn't apply:
//           this kernel is LDS-bound at 1 block/CU (96 KiB), so VGPR can grow
//           to 256 without occupancy loss. Watch WRITE_SIZE for spill.
__global__ __launch_bounds__(512) void k_gemm_fused(
    const unsigned short* __restrict__ Abf, const unsigned short* __restrict__ Bbf,
    const float* __restrict__ bbase, const float* __restrict__ t_ws,
    const float* __restrict__ bk_ws, const float* __restrict__ Bl,
    const float* __restrict__ Wu, const float* __restrict__ alphap,
    float* __restrict__ out)
{
  extern __shared__ unsigned short smem[];    // 3 bufs x 32 KiB = 96 KiB
  const int tid = threadIdx.x;
  const int l = tid & 63;
  const int w = __builtin_amdgcn_readfirstlane(tid >> 6);   // 0..7
  const int wr = w >> 2, wc = w & 3;                        // 2M x 4N

  // XCD-square map: XCD k owns row-panels [(k&3)*8,+8) x col-panels [(k>>2)*8,+8)
  const int bid = blockIdx.x;
  const int xcd = bid & 7;
  const int idx = bid >> 3;                  // 0..63 within XCD
  const int rowBase = ((xcd & 3) * 8 + (idx >> 3)) * 256;
  const int colBase = ((xcd >> 2) * 8 + (idx & 7)) * 256;

  v4f acc[8][4];
  const v4f z4 = {0.f, 0.f, 0.f, 0.f};
  #pragma unroll
  for (int m = 0; m < 8; ++m)
    #pragma unroll
    for (int n = 0; n < 4; ++n) acc[m][n] = z4;

  const int kperm = (l & 3) ^ ((l >> 3) & 3);
  const unsigned short* gA0 = Abf + (size_t)(rowBase + w*32 + (l>>2))*DD + kperm*8;
  const unsigned short* gB0 = Bbf + (size_t)(colBase + w*32 + (l>>2))*DD + kperm*8;

  unsigned short* a0 = &smem[w*1024];
  unsigned short* b0 = &smem[8192 + w*1024];

  const int sx = (l >> 4) ^ ((l >> 1) & 3);
  const unsigned short* pa = &smem[(wr*128 + (l&15))*32 + sx*8];
  const unsigned short* pb = &smem[8192 + (wc*64 + (l&15))*32 + sx*8];

#define ISSUE_A(b, kt) { const size_t go = (size_t)(kt)*32;                        \
    gload16(gA0 + go,                 a0 + (b)*16384);                             \
    gload16(gA0 + go + (size_t)16*DD, a0 + (b)*16384 + 512); }
#define ISSUE_B(b, kt) { const size_t go = (size_t)(kt)*32;                        \
    gload16(gB0 + go,                 b0 + (b)*16384);                             \
    gload16(gB0 + go + (size_t)16*DD, b0 + (b)*16384 + 512); }

#define TILE_BODY(cb, nb, kt2, STAGE, WAITOP) {                                    \
    v8s bf_[4], af_[4];                                                            \
    _Pragma("unroll")                                                              \
    for (int n = 0; n < 4; ++n) bf_[n] = *(const v8s*)(pb + (cb)*16384 + n*512);   \
    _Pragma("unroll")                                                              \
    for (int m = 0; m < 4; ++m) af_[m] = *(const v8s*)(pa + (cb)*16384 + m*512);   \
    if (STAGE){ ISSUE_A(nb, kt2); }                                                \
    asm volatile("" ::: "memory");                                                 \
    __builtin_amdgcn_s_barrier();                                                  \
    __builtin_amdgcn_s_setprio(1);                                                 \
    _Pragma("unroll")                                                              \
    for (int m = 0; m < 4; ++m)                                                    \
      _Pragma("unroll")                                                            \
      for (int n = 0; n < 4; ++n)                                                  \
        acc[m][n] = __builtin_amdgcn_mfma_f32_16x16x32_bf16(af_[m], bf_[n], acc[m][n], 0, 0, 0); \
    __builtin_amdgcn_s_setprio(0);                                                 \
    __builtin_amdgcn_s_barrier();                                                  \
    _Pragma("unroll")                                                              \
    for (int m = 0; m < 4; ++m) af_[m] = *(const v8s*)(pa + (cb)*16384 + (m+4)*512); \
    if (STAGE){ ISSUE_B(nb, kt2); }                                                \
    WAITOP;                                                                        \
    __builtin_amdgcn_s_barrier();                                                  \
    __builtin_amdgcn_s_setprio(1);                                                 \
    _Pragma("unroll")                                                              \
    for (int m = 0; m < 4; ++m)                                                    \
      _Pragma("unroll")                                                            \
      for (int n = 0; n < 4; ++n)                                                  \
        acc[m+4][n] = __builtin_amdgcn_mfma_f32_16x16x32_bf16(af_[m], bf_[n], acc[m+4][n], 0, 0, 0); \
    __builtin_amdgcn_s_setprio(0);                                                 \
    __builtin_amdgcn_s_barrier();                                                  \
}

#define W4 asm volatile("s_waitcnt vmcnt(4)" ::: "memory")
#define W0 asm volatile("s_waitcnt vmcnt(0)" ::: "memory")

  ISSUE_A(0, 0); ISSUE_B(0, 0);
  ISSUE_A(1, 1); ISSUE_B(1, 1);
  W4;
  __builtin_amdgcn_s_barrier();

  for (int t = 0; t < 126; t += 3){
    TILE_BODY(0, 2, t+2, 1, W4);
    TILE_BODY(1, 0, t+3, 1, W4);
    TILE_BODY(2, 1, t+4, 1, W4);
  }
  TILE_BODY(0, 0, 0, 0, W0);
  TILE_BODY(1, 0, 0, 0, );

#undef TILE_BODY
#undef ISSUE_A
#undef ISSUE_B
#undef W4
#undef W0

  // ---- register-resident epilogue (fast_tanh; LDS-bound kernel -> VGPR growth free) ----
  const float alpha = alphap[0];
  const int lhi = l >> 4, llo = l & 15;
  #pragma unroll
  for (int nc = 0; nc < 2; ++nc){
    float4 cb4[2][4]; float4 wu4[2][2]; float bbv[2];
    #pragma unroll
    for (int nn = 0; nn < 2; ++nn){
      const int n = nc*2 + nn;
      const int col = colBase + wc*64 + n*16 + llo;
      const float4* pB = (const float4*)(Bl + (size_t)col*16);
      cb4[nn][0] = pB[0]; cb4[nn][1] = pB[1]; cb4[nn][2] = pB[2]; cb4[nn][3] = pB[3];
      const float4* pW = (const float4*)(Wu + (size_t)col*8);
      wu4[nn][0] = pW[0]; wu4[nn][1] = pW[1];
      bbv[nn] = bbase[col];
    }
    #pragma unroll
    for (int m = 0; m < 8; ++m){
      #pragma unroll
      for (int j = 0; j < 4; ++j){
        const int rl = rowBase + wr*128 + m*16 + lhi*4 + j;
        const float4* pT = (const float4*)(t_ws + (size_t)rl*16);
        float4 t0 = pT[0], t1 = pT[1], t2 = pT[2], t3 = pT[3];
        const float4* pK = (const float4*)(bk_ws + (size_t)rl*8);
        float4 b0 = pK[0], b1 = pK[1];
        #pragma unroll
        for (int nn = 0; nn < 2; ++nn){
          const int n = nc*2 + nn;
          float lo = dot4(t0, cb4[nn][0]) + dot4(t1, cb4[nn][1])
                   + dot4(t2, cb4[nn][2]) + dot4(t3, cb4[nn][3]);
          float g  = dot4(b0, wu4[nn][0]) + dot4(b1, wu4[nn][1]);
          float val = acc[m][n][j] + bbv[nn] + (1.f + alpha*fast_tanh(g)) * (lo + lo);
          out[(size_t)rl*DD + (size_t)(colBase + wc*64 + n*16 + llo)] = val;
        }
      }
    }
  }
}

// ---------------- fallback GEMM (no ws): reg-staged fp32->bf16, fused epilogue ----------------
__global__ __launch_bounds__(256) void k_gemm_none(
    const float* __restrict__ Af, const float* __restrict__ Bf,
    const float* __restrict__ bbase, const float* __restrict__ t_ws,
    const float* __restrict__ bk_ws, const float* __restrict__ Bl,
    const float* __restrict__ Wu, const float* __restrict__ alphap,
    float* __restrict__ out)
{
  __shared__ unsigned short sA[128*32];
  __shared__ unsigned short sB[128*32];
  const int tid = threadIdx.x;
  const int l = tid & 63;
  const int w = __builtin_amdgcn_readfirstlane(tid >> 6);
  const int wr = w >> 1, wc = w & 1;
  const int rowBase = blockIdx.y * 128;
  const int colBase = blockIdx.x * 128;

  v4f acc[4][4];
  const v4f z4 = {0.f, 0.f, 0.f, 0.f};
  #pragma unroll
  for (int m = 0; m < 4; ++m)
    #pragma unroll
    for (int n = 0; n < 4; ++n) acc[m][n] = z4;

  const unsigned short* pa = &sA[(wr*64 + (l&15))*32 + (l>>4)*8];
  const unsigned short* pb = &sB[(wc*64 + (l&15))*32 + (l>>4)*8];

  for (int kt = 0; kt < 128; ++kt){
    #pragma unroll
    for (int q = 0; q < 4; ++q){
      const int f = tid + 256*q;
      const int row = f >> 3, kp = f & 7;
      float4 va = ((const float4*)Af)[(size_t)(rowBase+row)*1024 + kt*8 + kp];
      *(ushort4*)&sA[row*32 + kp*4] = cvt4(va);
      float4 vb = ((const float4*)Bf)[(size_t)(colBase+row)*1024 + kt*8 + kp];
      *(ushort4*)&sB[row*32 + kp*4] = cvt4(vb);
    }
    __syncthreads();
    v8s af[4], bfv[4];
    #pragma unroll
    for (int m = 0; m < 4; ++m) af[m]  = *(const v8s*)(pa + m*512);
    #pragma unroll
    for (int n = 0; n < 4; ++n) bfv[n] = *(const v8s*)(pb + n*512);
    #pragma unroll
    for (int m = 0; m < 4; ++m)
      #pragma unroll
      for (int n = 0; n < 4; ++n)
        acc[m][n] = __builtin_amdgcn_mfma_f32_16x16x32_bf16(af[m], bfv[n], acc[m][n], 0, 0, 0);
    __syncthreads();
  }

  const float alpha = alphap[0];
  const int lhi = l >> 4, llo = l & 15;
  #pragma unroll
  for (int m = 0; m < 4; ++m)
    #pragma unroll
    for (int n = 0; n < 4; ++n)
      #pragma unroll
      for (int j = 0; j < 4; ++j){
        const int rl = rowBase + wr*64 + m*16 + lhi*4 + j;
        const int cl = colBase + wc*64 + n*16 + llo;
        const float4* pT = (const float4*)(t_ws + (size_t)rl*16);
        const float4* pB2 = (const float4*)(Bl + (size_t)cl*16);
        float lo = dot4(pT[0], pB2[0]) + dot4(pT[1], pB2[1])
                 + dot4(pT[2], pB2[2]) + dot4(pT[3], pB2[3]);
        const float4* pK = (const float4*)(bk_ws + (size_t)rl*8);
        const float4* pW = (const float4*)(Wu + (size_t)cl*8);
        float g = dot4(pK[0], pW[0]) + dot4(pK[1], pW[1]);
        out[(size_t)rl*DD + cl] = acc[m][n][j] + bbase[cl]
                                + (1.f + alpha*fast_tanh(g)) * (lo + lo);
      }
}

extern "C" void kernel_launch(void* const* d_in, const int* in_sizes, int n_in,
                              void* d_out, int out_size, void* d_ws, size_t ws_size,
                              hipStream_t stream)
{
  const float* x   = (const float*)d_in[0];
  const float* Wb  = (const float*)d_in[1];
  const float* bb  = (const float*)d_in[2];
  const float* Am  = (const float*)d_in[3];
  const float* Bl  = (const float*)d_in[4];
  const float* lnw = (const float*)d_in[5];
  const float* lnb = (const float*)d_in[6];
  const float* Wd  = (const float*)d_in[7];
  const float* Wu  = (const float*)d_in[8];
  const float* al  = (const float*)d_in[9];
  float* out = (float*)d_out;

  char* ws = (char*)d_ws;
  float* t_ws  = (float*)ws;                       // 512 KiB
  float* bk_ws = (float*)(ws + 524288);            // 256 KiB
  float* cL    = (float*)(ws + 786432);
  float* cB    = (float*)(ws + 786432 + 64);
  const size_t SMALL = 1ull << 20;
  unsigned short* wbf = (unsigned short*)(ws + SMALL);                  // 32 MiB
  unsigned short* xbf = (unsigned short*)(ws + SMALL + (32ull << 20));  // 64 MiB

  const bool haveX = ws_size >= SMALL + (96ull << 20);

  k_cwd<<<1, 256, 0, stream>>>(lnw, lnb, Wd, cL, cB);
  k_rows_t<<<2048, 256, 0, stream>>>(x, Am, t_ws, xbf, haveX ? 1 : 0);
  k_rows_b<<<2048, 256, 0, stream>>>(x, lnw, Wd, cL, cB, bk_ws);

  if (haveX){
    k_convert_bf16<<<2048, 256, 0, stream>>>(Wb, wbf, 4194304);
    k_gemm_fused<<<512, 512, 98304, stream>>>(xbf, wbf, bb, t_ws, bk_ws, Bl, Wu, al, out);
  } else {
    dim3 gg(32, 64);
    k_gemm_none<<<gg, 256, 0, stream>>>(x, Wb, bb, t_ws, bk_ws, Bl, Wu, al, out);
  }
}

// Round 20
// 629.392 us; speedup vs baseline: 2.0927x; 2.0927x over previous
//
#include <hip/hip_runtime.h>
#include <hip/hip_bf16.h>
#include <stdint.h>
#include <math.h>

#define DD 4096

typedef float v4f __attribute__((ext_vector_type(4)));
typedef short v8s __attribute__((ext_vector_type(8)));

__device__ __forceinline__ unsigned short f2bf(float f){
  union { float f; uint32_t u; } v; v.f = f;
  uint32_t u = v.u;
  uint32_t r = (u + 0x7fffu + ((u >> 16) & 1u)) >> 16;
  return (unsigned short)r;
}
__device__ __forceinline__ ushort4 cvt4(float4 v){
  ushort4 o; o.x = f2bf(v.x); o.y = f2bf(v.y); o.z = f2bf(v.z); o.w = f2bf(v.w); return o;
}
__device__ __forceinline__ float dot4(float4 a, float4 b){
  return a.x*b.x + a.y*b.y + a.z*b.z + a.w*b.w;
}
__device__ __forceinline__ float wred(float v){
  #pragma unroll
  for (int m = 32; m >= 1; m >>= 1) v += __shfl_xor(v, m, 64);
  return v;
}
__device__ __forceinline__ float fast_tanh(float x){
  float e = __expf(2.f * x);
  return __fdividef(e - 1.f, e + 1.f);
}
__device__ __forceinline__ void gload16(const void* g, void* l){
  __builtin_amdgcn_global_load_lds((const __attribute__((address_space(1))) void*)g,
                                   (__attribute__((address_space(3))) void*)l, 16, 0, 0);
}

// ---------------- fp32 -> bf16 convert: grid-strided, 8 float4/thread ----------------
__global__ __launch_bounds__(256) void k_convert_bf16(const float* __restrict__ src,
                                                      unsigned short* __restrict__ dst, int n4){
  int i = blockIdx.x * 256 + threadIdx.x;
  #pragma unroll
  for (int q = 0; q < 8; ++q){
    if (i < n4){
      float4 v = ((const float4*)src)[i];
      ((ushort4*)dst)[i] = cvt4(v);
    }
    i += 524288;   // 2048 blocks * 256 threads
  }
}

// ---------------- cL[k]=dot(ln_w,Wd[k]); cB[k]=dot(ln_b,Wd[k]) ----------------
__global__ __launch_bounds__(256) void k_cwd(const float* __restrict__ lnw,
    const float* __restrict__ lnb, const float* __restrict__ wd,
    float* __restrict__ cL, float* __restrict__ cB)
{
  const int tid = threadIdx.x;
  float aL[8], aB[8];
  #pragma unroll
  for (int k = 0; k < 8; ++k){ aL[k] = 0.f; aB[k] = 0.f; }
  for (int i = tid; i < 1024; i += 256){
    float4 w4 = ((const float4*)lnw)[i];
    float4 b4 = ((const float4*)lnb)[i];
    #pragma unroll
    for (int k = 0; k < 8; ++k){
      float4 d4 = ((const float4*)wd)[(size_t)k*1024 + i];
      aL[k] += dot4(w4, d4);
      aB[k] += dot4(b4, d4);
    }
  }
  __shared__ float sp[4][16];
  const int w = tid >> 6, lane = tid & 63;
  #pragma unroll
  for (int k = 0; k < 8; ++k){
    float v = wred(aL[k]); if (lane == 0) sp[w][k] = v;
    v = wred(aB[k]);       if (lane == 0) sp[w][8+k] = v;
  }
  __syncthreads();
  if (tid < 8)       cL[tid]   = sp[0][tid] + sp[1][tid] + sp[2][tid] + sp[3][tid];
  else if (tid < 16) cB[tid-8] = sp[0][tid] + sp[1][tid] + sp[2][tid] + sp[3][tid];
}

// ---------------- row pass A: t = x.A^T (+ x->bf16), 4 rows/block [r18-measured] ----------------
__global__ __launch_bounds__(256) void k_rows_t(const float* __restrict__ x,
    const float* __restrict__ Am, float* __restrict__ t_ws,
    unsigned short* __restrict__ xbf, int writeBf)
{
  const int row0 = blockIdx.x * 4;
  const int tid = threadIdx.x;
  float dA[4][16];
  #pragma unroll
  for (int rr = 0; rr < 4; ++rr)
    #pragma unroll
    for (int r = 0; r < 16; ++r) dA[rr][r] = 0.f;

  #pragma unroll
  for (int i = 0; i < 4; ++i){
    const int d4 = tid + 256*i;
    float4 xv[4];
    #pragma unroll
    for (int rr = 0; rr < 4; ++rr){
      xv[rr] = ((const float4*)x)[(size_t)(row0+rr)*1024 + d4];
      if (writeBf) ((ushort4*)xbf)[(size_t)(row0+rr)*1024 + d4] = cvt4(xv[rr]);
    }
    #pragma unroll
    for (int r = 0; r < 16; ++r){
      float4 a4 = ((const float4*)Am)[(size_t)r*1024 + d4];
      #pragma unroll
      for (int rr = 0; rr < 4; ++rr) dA[rr][r] += dot4(xv[rr], a4);
    }
  }
  __shared__ float sp[4][64];
  const int w = tid >> 6, lane = tid & 63;
  #pragma unroll
  for (int rr = 0; rr < 4; ++rr)
    #pragma unroll
    for (int r = 0; r < 16; ++r){
      float v = wred(dA[rr][r]);
      if (lane == 0) sp[w][rr*16 + r] = v;
    }
  __syncthreads();
  if (tid < 64){
    t_ws[(size_t)row0*16 + tid] = sp[0][tid] + sp[1][tid] + sp[2][tid] + sp[3][tid];
  }
}

// ---------------- row pass B: bk = silu(LN(x).Wd^T), 4 rows/block [r18-measured] ----------------
__global__ __launch_bounds__(256) void k_rows_b(const float* __restrict__ x,
    const float* __restrict__ lnw, const float* __restrict__ wd,
    const float* __restrict__ cL, const float* __restrict__ cB,
    float* __restrict__ bk_ws)
{
  const int row0 = blockIdx.x * 4;
  const int tid = threadIdx.x;
  float sum[4] = {0,0,0,0}, ssq[4] = {0,0,0,0};
  float dW[4][8];
  #pragma unroll
  for (int rr = 0; rr < 4; ++rr)
    #pragma unroll
    for (int k = 0; k < 8; ++k) dW[rr][k] = 0.f;

  #pragma unroll
  for (int i = 0; i < 4; ++i){
    const int d4 = tid + 256*i;
    float4 w4 = ((const float4*)lnw)[d4];
    float4 xv[4];
    #pragma unroll
    for (int rr = 0; rr < 4; ++rr){
      xv[rr] = ((const float4*)x)[(size_t)(row0+rr)*1024 + d4];
      sum[rr] += xv[rr].x + xv[rr].y + xv[rr].z + xv[rr].w;
      ssq[rr] += dot4(xv[rr], xv[rr]);
    }
    #pragma unroll
    for (int k = 0; k < 8; ++k){
      float4 wk = ((const float4*)wd)[(size_t)k*1024 + d4];
      float4 lw; lw.x = w4.x*wk.x; lw.y = w4.y*wk.y; lw.z = w4.z*wk.z; lw.w = w4.w*wk.w;
      #pragma unroll
      for (int rr = 0; rr < 4; ++rr) dW[rr][k] += dot4(xv[rr], lw);
    }
  }
  __shared__ float sp[4][40];
  const int w = tid >> 6, lane = tid & 63;
  #pragma unroll
  for (int rr = 0; rr < 4; ++rr){
    float v;
    v = wred(sum[rr]); if (lane == 0) sp[w][rr*10 + 0] = v;
    v = wred(ssq[rr]); if (lane == 0) sp[w][rr*10 + 1] = v;
    #pragma unroll
    for (int k = 0; k < 8; ++k){
      v = wred(dW[rr][k]); if (lane == 0) sp[w][rr*10 + 2 + k] = v;
    }
  }
  __syncthreads();
  __shared__ float st[40];
  if (tid < 40) st[tid] = sp[0][tid] + sp[1][tid] + sp[2][tid] + sp[3][tid];
  __syncthreads();
  if (tid < 32){
    const int rr = tid >> 3, k = tid & 7;
    const float s  = st[rr*10 + 0];
    const float s2 = st[rr*10 + 1];
    const float mu = s * (1.f/4096.f);
    const float var = s2 * (1.f/4096.f) - mu*mu;
    const float istd = rsqrtf(var + 1e-5f);
    const float raw = istd*st[rr*10 + 2 + k] - mu*istd*cL[k] + cB[k];
    bk_ws[(size_t)(row0+rr)*8 + k] = raw / (1.f + __expf(-raw));   // silu
  }
}

// ---------------- fused GEMM: r16/r18 structure + XCD-square map, tanhf epilogue ----
// K-loop: phase-split, 3-buf (96 KiB), counted vmcnt(4) ledger, kperm/sx swizzle
// (conflicts==0), setprio — the measured-356µs structure.
// ONLY change vs r18: XCD map 4x16 -> 8x8 panels per XCD (per-XCD unique operand
// bytes 40 -> 32 MB; predicted FETCH 345 -> ~265 MB). Address arithmetic only.
// Epilogue keeps libm tanhf: the call is a scheduling fence. Inlining fast_tanh
// here spilled catastrophically THREE times (r4, r5, r19: WRITE 221MB -> 1.7GB).
// DO NOT inline the tanh.
__global__ __launch_bounds__(512) void k_gemm_fused(
    const unsigned short* __restrict__ Abf, const unsigned short* __restrict__ Bbf,
    const float* __restrict__ bbase, const float* __restrict__ t_ws,
    const float* __restrict__ bk_ws, const float* __restrict__ Bl,
    const float* __restrict__ Wu, const float* __restrict__ alphap,
    float* __restrict__ out)
{
  extern __shared__ unsigned short smem[];    // 3 bufs x 32 KiB = 96 KiB
  const int tid = threadIdx.x;
  const int l = tid & 63;
  const int w = __builtin_amdgcn_readfirstlane(tid >> 6);   // 0..7
  const int wr = w >> 2, wc = w & 3;                        // 2M x 4N

  // XCD-square map: XCD k owns row-panels [(k&3)*8,+8) x col-panels [(k>>2)*8,+8)
  const int bid = blockIdx.x;
  const int xcd = bid & 7;
  const int idx = bid >> 3;                  // 0..63 within XCD
  const int rowBase = ((xcd & 3) * 8 + (idx >> 3)) * 256;
  const int colBase = ((xcd >> 2) * 8 + (idx & 7)) * 256;

  v4f acc[8][4];
  const v4f z4 = {0.f, 0.f, 0.f, 0.f};
  #pragma unroll
  for (int m = 0; m < 8; ++m)
    #pragma unroll
    for (int n = 0; n < 4; ++n) acc[m][n] = z4;

  const int kperm = (l & 3) ^ ((l >> 3) & 3);
  const unsigned short* gA0 = Abf + (size_t)(rowBase + w*32 + (l>>2))*DD + kperm*8;
  const unsigned short* gB0 = Bbf + (size_t)(colBase + w*32 + (l>>2))*DD + kperm*8;

  unsigned short* a0 = &smem[w*1024];
  unsigned short* b0 = &smem[8192 + w*1024];

  const int sx = (l >> 4) ^ ((l >> 1) & 3);
  const unsigned short* pa = &smem[(wr*128 + (l&15))*32 + sx*8];
  const unsigned short* pb = &smem[8192 + (wc*64 + (l&15))*32 + sx*8];

#define ISSUE_A(b, kt) { const size_t go = (size_t)(kt)*32;                        \
    gload16(gA0 + go,                 a0 + (b)*16384);                             \
    gload16(gA0 + go + (size_t)16*DD, a0 + (b)*16384 + 512); }
#define ISSUE_B(b, kt) { const size_t go = (size_t)(kt)*32;                        \
    gload16(gB0 + go,                 b0 + (b)*16384);                             \
    gload16(gB0 + go + (size_t)16*DD, b0 + (b)*16384 + 512); }

#define TILE_BODY(cb, nb, kt2, STAGE, WAITOP) {                                    \
    v8s bf_[4], af_[4];                                                            \
    _Pragma("unroll")                                                              \
    for (int n = 0; n < 4; ++n) bf_[n] = *(const v8s*)(pb + (cb)*16384 + n*512);   \
    _Pragma("unroll")                                                              \
    for (int m = 0; m < 4; ++m) af_[m] = *(const v8s*)(pa + (cb)*16384 + m*512);   \
    if (STAGE){ ISSUE_A(nb, kt2); }                                                \
    asm volatile("" ::: "memory");                                                 \
    __builtin_amdgcn_s_barrier();                                                  \
    __builtin_amdgcn_s_setprio(1);                                                 \
    _Pragma("unroll")                                                              \
    for (int m = 0; m < 4; ++m)                                                    \
      _Pragma("unroll")                                                            \
      for (int n = 0; n < 4; ++n)                                                  \
        acc[m][n] = __builtin_amdgcn_mfma_f32_16x16x32_bf16(af_[m], bf_[n], acc[m][n], 0, 0, 0); \
    __builtin_amdgcn_s_setprio(0);                                                 \
    __builtin_amdgcn_s_barrier();                                                  \
    _Pragma("unroll")                                                              \
    for (int m = 0; m < 4; ++m) af_[m] = *(const v8s*)(pa + (cb)*16384 + (m+4)*512); \
    if (STAGE){ ISSUE_B(nb, kt2); }                                                \
    WAITOP;                                                                        \
    __builtin_amdgcn_s_barrier();                                                  \
    __builtin_amdgcn_s_setprio(1);                                                 \
    _Pragma("unroll")                                                              \
    for (int m = 0; m < 4; ++m)                                                    \
      _Pragma("unroll")                                                            \
      for (int n = 0; n < 4; ++n)                                                  \
        acc[m+4][n] = __builtin_amdgcn_mfma_f32_16x16x32_bf16(af_[m], bf_[n], acc[m+4][n], 0, 0, 0); \
    __builtin_amdgcn_s_setprio(0);                                                 \
    __builtin_amdgcn_s_barrier();                                                  \
}

#define W4 asm volatile("s_waitcnt vmcnt(4)" ::: "memory")
#define W0 asm volatile("s_waitcnt vmcnt(0)" ::: "memory")

  ISSUE_A(0, 0); ISSUE_B(0, 0);
  ISSUE_A(1, 1); ISSUE_B(1, 1);
  W4;
  __builtin_amdgcn_s_barrier();

  for (int t = 0; t < 126; t += 3){
    TILE_BODY(0, 2, t+2, 1, W4);
    TILE_BODY(1, 0, t+3, 1, W4);
    TILE_BODY(2, 1, t+4, 1, W4);
  }
  TILE_BODY(0, 0, 0, 0, W0);
  TILE_BODY(1, 0, 0, 0, );

#undef TILE_BODY
#undef ISSUE_A
#undef ISSUE_B
#undef W4
#undef W0

  // ---- register-resident epilogue (libm tanhf — scheduling fence, keep it) ----
  const float alpha = alphap[0];
  const int lhi = l >> 4, llo = l & 15;
  #pragma unroll
  for (int nc = 0; nc < 2; ++nc){
    float4 cb4[2][4]; float4 wu4[2][2]; float bbv[2];
    #pragma unroll
    for (int nn = 0; nn < 2; ++nn){
      const int n = nc*2 + nn;
      const int col = colBase + wc*64 + n*16 + llo;
      const float4* pB = (const float4*)(Bl + (size_t)col*16);
      cb4[nn][0] = pB[0]; cb4[nn][1] = pB[1]; cb4[nn][2] = pB[2]; cb4[nn][3] = pB[3];
      const float4* pW = (const float4*)(Wu + (size_t)col*8);
      wu4[nn][0] = pW[0]; wu4[nn][1] = pW[1];
      bbv[nn] = bbase[col];
    }
    #pragma unroll
    for (int m = 0; m < 8; ++m){
      #pragma unroll
      for (int j = 0; j < 4; ++j){
        const int rl = rowBase + wr*128 + m*16 + lhi*4 + j;
        const float4* pT = (const float4*)(t_ws + (size_t)rl*16);
        float4 t0 = pT[0], t1 = pT[1], t2 = pT[2], t3 = pT[3];
        const float4* pK = (const float4*)(bk_ws + (size_t)rl*8);
        float4 b0 = pK[0], b1 = pK[1];
        #pragma unroll
        for (int nn = 0; nn < 2; ++nn){
          const int n = nc*2 + nn;
          float lo = dot4(t0, cb4[nn][0]) + dot4(t1, cb4[nn][1])
                   + dot4(t2, cb4[nn][2]) + dot4(t3, cb4[nn][3]);
          float g  = dot4(b0, wu4[nn][0]) + dot4(b1, wu4[nn][1]);
          float val = acc[m][n][j] + bbv[nn] + (1.f + alpha*tanhf(g)) * (lo + lo);
          out[(size_t)rl*DD + (size_t)(colBase + wc*64 + n*16 + llo)] = val;
        }
      }
    }
  }
}

// ---------------- fallback GEMM (no ws): reg-staged fp32->bf16, fused epilogue ----------------
__global__ __launch_bounds__(256) void k_gemm_none(
    const float* __restrict__ Af, const float* __restrict__ Bf,
    const float* __restrict__ bbase, const float* __restrict__ t_ws,
    const float* __restrict__ bk_ws, const float* __restrict__ Bl,
    const float* __restrict__ Wu, const float* __restrict__ alphap,
    float* __restrict__ out)
{
  __shared__ unsigned short sA[128*32];
  __shared__ unsigned short sB[128*32];
  const int tid = threadIdx.x;
  const int l = tid & 63;
  const int w = __builtin_amdgcn_readfirstlane(tid >> 6);
  const int wr = w >> 1, wc = w & 1;
  const int rowBase = blockIdx.y * 128;
  const int colBase = blockIdx.x * 128;

  v4f acc[4][4];
  const v4f z4 = {0.f, 0.f, 0.f, 0.f};
  #pragma unroll
  for (int m = 0; m < 4; ++m)
    #pragma unroll
    for (int n = 0; n < 4; ++n) acc[m][n] = z4;

  const unsigned short* pa = &sA[(wr*64 + (l&15))*32 + (l>>4)*8];
  const unsigned short* pb = &sB[(wc*64 + (l&15))*32 + (l>>4)*8];

  for (int kt = 0; kt < 128; ++kt){
    #pragma unroll
    for (int q = 0; q < 4; ++q){
      const int f = tid + 256*q;
      const int row = f >> 3, kp = f & 7;
      float4 va = ((const float4*)Af)[(size_t)(rowBase+row)*1024 + kt*8 + kp];
      *(ushort4*)&sA[row*32 + kp*4] = cvt4(va);
      float4 vb = ((const float4*)Bf)[(size_t)(colBase+row)*1024 + kt*8 + kp];
      *(ushort4*)&sB[row*32 + kp*4] = cvt4(vb);
    }
    __syncthreads();
    v8s af[4], bfv[4];
    #pragma unroll
    for (int m = 0; m < 4; ++m) af[m]  = *(const v8s*)(pa + m*512);
    #pragma unroll
    for (int n = 0; n < 4; ++n) bfv[n] = *(const v8s*)(pb + n*512);
    #pragma unroll
    for (int m = 0; m < 4; ++m)
      #pragma unroll
      for (int n = 0; n < 4; ++n)
        acc[m][n] = __builtin_amdgcn_mfma_f32_16x16x32_bf16(af[m], bfv[n], acc[m][n], 0, 0, 0);
    __syncthreads();
  }

  const float alpha = alphap[0];
  const int lhi = l >> 4, llo = l & 15;
  #pragma unroll
  for (int m = 0; m < 4; ++m)
    #pragma unroll
    for (int n = 0; n < 4; ++n)
      #pragma unroll
      for (int j = 0; j < 4; ++j){
        const int rl = rowBase + wr*64 + m*16 + lhi*4 + j;
        const int cl = colBase + wc*64 + n*16 + llo;
        const float4* pT = (const float4*)(t_ws + (size_t)rl*16);
        const float4* pB2 = (const float4*)(Bl + (size_t)cl*16);
        float lo = dot4(pT[0], pB2[0]) + dot4(pT[1], pB2[1])
                 + dot4(pT[2], pB2[2]) + dot4(pT[3], pB2[3]);
        const float4* pK = (const float4*)(bk_ws + (size_t)rl*8);
        const float4* pW = (const float4*)(Wu + (size_t)cl*8);
        float g = dot4(pK[0], pW[0]) + dot4(pK[1], pW[1]);
        out[(size_t)rl*DD + cl] = acc[m][n][j] + bbase[cl]
                                + (1.f + alpha*fast_tanh(g)) * (lo + lo);
      }
}

extern "C" void kernel_launch(void* const* d_in, const int* in_sizes, int n_in,
                              void* d_out, int out_size, void* d_ws, size_t ws_size,
                              hipStream_t stream)
{
  const float* x   = (const float*)d_in[0];
  const float* Wb  = (const float*)d_in[1];
  const float* bb  = (const float*)d_in[2];
  const float* Am  = (const float*)d_in[3];
  const float* Bl  = (const float*)d_in[4];
  const float* lnw = (const float*)d_in[5];
  const float* lnb = (const float*)d_in[6];
  const float* Wd  = (const float*)d_in[7];
  const float* Wu  = (const float*)d_in[8];
  const float* al  = (const float*)d_in[9];
  float* out = (float*)d_out;

  char* ws = (char*)d_ws;
  float* t_ws  = (float*)ws;                       // 512 KiB
  float* bk_ws = (float*)(ws + 524288);            // 256 KiB
  float* cL    = (float*)(ws + 786432);
  float* cB    = (float*)(ws + 786432 + 64);
  const size_t SMALL = 1ull << 20;
  unsigned short* wbf = (unsigned short*)(ws + SMALL);                  // 32 MiB
  unsigned short* xbf = (unsigned short*)(ws + SMALL + (32ull << 20));  // 64 MiB

  const bool haveX = ws_size >= SMALL + (96ull << 20);

  k_cwd<<<1, 256, 0, stream>>>(lnw, lnb, Wd, cL, cB);
  k_rows_t<<<2048, 256, 0, stream>>>(x, Am, t_ws, xbf, haveX ? 1 : 0);
  k_rows_b<<<2048, 256, 0, stream>>>(x, lnw, Wd, cL, cB, bk_ws);

  if (haveX){
    k_convert_bf16<<<2048, 256, 0, stream>>>(Wb, wbf, 4194304);
    k_gemm_fused<<<512, 512, 98304, stream>>>(xbf, wbf, bb, t_ws, bk_ws, Bl, Wu, al, out);
  } else {
    dim3 gg(32, 64);
    k_gemm_none<<<gg, 256, 0, stream>>>(x, Wb, bb, t_ws, bk_ws, Bl, Wu, al, out);
  }
}